// Round 1
// baseline (326.100 us; speedup 1.0000x reference)
//
#include <hip/hip_runtime.h>

#define B_ 4
#define C_ 1024
#define T_ 2048
#define NH 16
#define DH 64
#define TC 3072   // 3*C: rows [0,2048)=W_mem (K then V), [2048,3072)=W_q

typedef __attribute__((ext_vector_type(8))) short short8;
typedef __attribute__((ext_vector_type(4))) short short4v;
typedef __attribute__((ext_vector_type(4))) float f32x4;

static __device__ __forceinline__ unsigned short f2bf(float f){
  unsigned int u = __builtin_bit_cast(unsigned int, f);
  u += 0x7fffu + ((u >> 16) & 1u);
  return (unsigned short)(u >> 16);
}

// ---------------- cast W_mem||W_q -> bf16 Wc[3072][1024] ----------------
__global__ __launch_bounds__(256) void cast_w_kernel(const float* __restrict__ Wmem,
                                                     const float* __restrict__ Wq,
                                                     unsigned short* __restrict__ Wc){
  size_t base = ((size_t)blockIdx.x*256 + threadIdx.x)*4;
  float4 v;
  if (base < (size_t)2048*1024) v = *(const float4*)(Wmem + base);
  else                          v = *(const float4*)(Wq + (base - (size_t)2048*1024));
  short4v o;
  o.x = (short)f2bf(v.x); o.y = (short)f2bf(v.y);
  o.z = (short)f2bf(v.z); o.w = (short)f2bf(v.w);
  *(short4v*)(Wc + base) = o;
}

// ---------------- transpose-cast x[B][C][T] f32 -> xT[B][T][C] bf16 ----------------
__global__ __launch_bounds__(256) void transpose_x_kernel(const float* __restrict__ x,
                                                          unsigned short* __restrict__ xT){
  __shared__ float tile[32][33];
  int b = blockIdx.z;
  int c0 = blockIdx.y*32, t0 = blockIdx.x*32;
  int tx = threadIdx.x, ty = threadIdx.y;
  const float* xp = x + ((size_t)b*C_ + c0)*T_ + t0;
  #pragma unroll
  for (int i=0;i<4;i++) tile[ty+8*i][tx] = xp[(size_t)(ty+8*i)*T_ + tx];
  __syncthreads();
  unsigned short* op = xT + ((size_t)b*T_ + t0)*C_ + c0;
  #pragma unroll
  for (int i=0;i<4;i++) op[(size_t)(ty+8*i)*C_ + tx] = f2bf(tile[tx][ty+8*i]);
}

// ---------------- projection GEMM: out[o][t] = sum_c Wc[o][c]*xT[b][t][c] ----------------
// 128x128 tile, BK=64, 4 waves, global_load_lds staging (m97 structure).
#define PBM 128
#define PBN 128
#define PBK 64

__global__ __launch_bounds__(256) void proj_gemm_kernel(const unsigned short* __restrict__ Wc,
    const unsigned short* __restrict__ xT,
    unsigned short* __restrict__ Kb, unsigned short* __restrict__ Vt,
    unsigned short* __restrict__ Qb){
  __shared__ unsigned short sA[PBM*PBK];   // [128 o][64 c] linear
  __shared__ unsigned short sB[PBN*PBK];   // [128 t][64 c] linear
  int b = blockIdx.y;
  int nbn = T_/PBN;
  int o0 = (int)(blockIdx.x / nbn)*PBM;
  int t0 = (int)(blockIdx.x % nbn)*PBN;
  int tid = threadIdx.x;
  int lane = tid & 63, wave = tid >> 6;
  int wr = wave >> 1, wc = wave & 1;
  f32x4 acc[4][4] = {};
  const unsigned short* Abase = Wc + (size_t)o0*C_;
  const unsigned short* Bbase = xT + ((size_t)b*T_ + t0)*C_;
  auto ldsA = (__attribute__((address_space(3))) char*)sA;
  auto ldsB = (__attribute__((address_space(3))) char*)sB;
  for (int k0=0; k0<C_; k0+=PBK){
    #pragma unroll
    for (int i=0;i<4;i++){
      int L  = wave*4096 + i*1024;       // wave-uniform LDS base; HW adds lane*16
      int Ll = L + lane*16;
      int row = Ll >> 7;                 // /128 bytes per row
      int jb  = Ll & 127;
      const char* srcA = (const char*)(Abase + (size_t)row*C_ + k0) + jb;
      const char* srcB = (const char*)(Bbase + (size_t)row*C_ + k0) + jb;
      __builtin_amdgcn_global_load_lds((const __attribute__((address_space(1))) void*)srcA,
                                       (__attribute__((address_space(3))) void*)(ldsA + L), 16, 0, 0);
      __builtin_amdgcn_global_load_lds((const __attribute__((address_space(1))) void*)srcB,
                                       (__attribute__((address_space(3))) void*)(ldsB + L), 16, 0, 0);
    }
    __syncthreads();
    #pragma unroll
    for (int ks=0; ks<2; ks++){
      short8 af[4], bfr[4];
      #pragma unroll
      for (int m=0;m<4;m++){
        int row = wr*64 + m*16 + (lane & 15);
        af[m] = *(const short8*)((const char*)sA + row*128 + ks*64 + ((lane>>4)*16));
      }
      #pragma unroll
      for (int n=0;n<4;n++){
        int row = wc*64 + n*16 + (lane & 15);
        bfr[n] = *(const short8*)((const char*)sB + row*128 + ks*64 + ((lane>>4)*16));
      }
      #pragma unroll
      for (int m=0;m<4;m++){
        #pragma unroll
        for (int n=0;n<4;n++)
          acc[m][n] = __builtin_amdgcn_mfma_f32_16x16x32_bf16(af[m], bfr[n], acc[m][n], 0, 0, 0);
      }
    }
    __syncthreads();
  }
  // epilogue: route to K [b,h,t,d] / Vt [b,h,d,t] / Q [b,h,t,d], all bf16
  int rowbase = o0 + wr*64;
  #pragma unroll
  for (int m=0;m<4;m++){
    int o = rowbase + m*16 + ((lane>>4)*4);
    #pragma unroll
    for (int n=0;n<4;n++){
      int t = t0 + wc*64 + n*16 + (lane & 15);
      f32x4 v = acc[m][n];
      if (o < C_){
        int h = o >> 6, d = o & 63;
        unsigned short* p = Kb + (((size_t)(b*NH + h)*T_ + t)*DH + d);
        short4v s; s.x=(short)f2bf(v.x); s.y=(short)f2bf(v.y);
        s.z=(short)f2bf(v.z); s.w=(short)f2bf(v.w);
        *(short4v*)p = s;
      } else if (o < 2*C_){
        int oo = o - C_;
        int h = oo >> 6, d = oo & 63;
        unsigned short* p = Vt + (((size_t)(b*NH + h)*DH + d)*T_ + t);
        p[0]    = f2bf(v.x);
        p[T_]   = f2bf(v.y);
        p[2*T_] = f2bf(v.z);
        p[3*T_] = f2bf(v.w);
      } else {
        int oo = o - 2*C_;
        int h = oo >> 6, d = oo & 63;
        unsigned short* p = Qb + (((size_t)(b*NH + h)*T_ + t)*DH + d);
        short4v s; s.x=(short)f2bf(v.x); s.y=(short)f2bf(v.y);
        s.z=(short)f2bf(v.z); s.w=(short)f2bf(v.w);
        *(short4v*)p = s;
      }
    }
  }
}

// ---------------- flash attention ----------------
// block = (b,h,qblk of 64 rows); 4 waves x 16 q-rows; KB=64 key tiles.
#define KB_ 64
#define PAD 88   // row stride in elems: 176 B -> 16B-aligned b128 reads, ~2-way banks

__global__ __launch_bounds__(256) void attn_kernel(const unsigned short* __restrict__ Qb,
    const unsigned short* __restrict__ Kb, const unsigned short* __restrict__ Vt,
    const int* __restrict__ mask, float* __restrict__ out){
  __shared__ unsigned short sK[KB_][PAD];     // K tile [key][d]
  __shared__ unsigned short sV[DH][PAD];      // V tile transposed [d][key]
  __shared__ unsigned short sP[4][16][PAD];   // per-wave P [qrow][key]
  int qblk = blockIdx.x;
  int bh = blockIdx.y;
  int b = bh >> 4;
  int tid = threadIdx.x, lane = tid & 63, wave = tid >> 6;
  int l15 = lane & 15, lg = lane >> 4;
  const unsigned short* Kbase = Kb + (size_t)bh*T_*DH;
  const unsigned short* Vbase = Vt + (size_t)bh*DH*T_;
  const int* mbase = mask + (size_t)b*T_;
  int qrow = qblk*64 + wave*16 + l15;
  const unsigned short* Qp = Qb + ((size_t)bh*T_ + qrow)*DH + lg*8;
  short8 qf0 = *(const short8*)(Qp);
  short8 qf1 = *(const short8*)(Qp + 32);
  f32x4 acco[4] = {};
  float mrun[4] = {-1e30f,-1e30f,-1e30f,-1e30f};
  float lrun[4] = {0.f,0.f,0.f,0.f};
  const float scale = 0.125f;
  for (int kt=0; kt<T_/KB_; kt++){
    #pragma unroll
    for (int i=0;i<2;i++){
      int chunk = tid + i*256;
      int row = chunk >> 3, c0 = (chunk & 7)*8;
      short8 kvv = *(const short8*)(Kbase + ((size_t)(kt*KB_ + row))*DH + c0);
      *(short8*)(&sK[row][c0]) = kvv;
      short8 vvv = *(const short8*)(Vbase + (size_t)row*T_ + kt*KB_ + c0);
      *(short8*)(&sV[row][c0]) = vvv;
    }
    __syncthreads();
    // S = Q K^T   (A=Q rows q, B=K^T cols key)
    f32x4 sacc[4] = {};
    #pragma unroll
    for (int n=0;n<4;n++){
      short8 kf0 = *(const short8*)(&sK[n*16 + l15][lg*8]);
      short8 kf1 = *(const short8*)(&sK[n*16 + l15][32 + lg*8]);
      sacc[n] = __builtin_amdgcn_mfma_f32_16x16x32_bf16(qf0, kf0, sacc[n], 0,0,0);
      sacc[n] = __builtin_amdgcn_mfma_f32_16x16x32_bf16(qf1, kf1, sacc[n], 0,0,0);
    }
    int mk0 = mbase[kt*KB_ +  0 + l15];
    int mk1 = mbase[kt*KB_ + 16 + l15];
    int mk2 = mbase[kt*KB_ + 32 + l15];
    int mk3 = mbase[kt*KB_ + 48 + l15];
    #pragma unroll
    for (int r=0;r<4;r++){
      float x0 = mk0 ? sacc[0][r]*scale : -1e30f;
      float x1 = mk1 ? sacc[1][r]*scale : -1e30f;
      float x2 = mk2 ? sacc[2][r]*scale : -1e30f;
      float x3 = mk3 ? sacc[3][r]*scale : -1e30f;
      float rm = fmaxf(fmaxf(x0,x1), fmaxf(x2,x3));
      #pragma unroll
      for (int off=1; off<16; off<<=1) rm = fmaxf(rm, __shfl_xor(rm, off));
      float mnew = fmaxf(mrun[r], rm);
      float alpha = __expf(mrun[r] - mnew);
      float p0 = __expf(x0 - mnew);
      float p1 = __expf(x1 - mnew);
      float p2 = __expf(x2 - mnew);
      float p3 = __expf(x3 - mnew);
      float rs = p0+p1+p2+p3;
      #pragma unroll
      for (int off=1; off<16; off<<=1) rs += __shfl_xor(rs, off);
      lrun[r] = lrun[r]*alpha + rs;
      mrun[r] = mnew;
      #pragma unroll
      for (int nd=0; nd<4; nd++) acco[nd][r] *= alpha;
      int prow = lg*4 + r;
      sP[wave][prow][ 0 + l15] = f2bf(p0);
      sP[wave][prow][16 + l15] = f2bf(p1);
      sP[wave][prow][32 + l15] = f2bf(p2);
      sP[wave][prow][48 + l15] = f2bf(p3);
    }
    // same-wave LDS write->read ordering
    asm volatile("s_waitcnt lgkmcnt(0)" ::: "memory");
    #pragma unroll
    for (int ks=0; ks<2; ks++){
      short8 pf = *(const short8*)(&sP[wave][l15][ks*32 + lg*8]);
      #pragma unroll
      for (int nd=0; nd<4; nd++){
        short8 vf = *(const short8*)(&sV[nd*16 + l15][ks*32 + lg*8]);
        acco[nd] = __builtin_amdgcn_mfma_f32_16x16x32_bf16(pf, vf, acco[nd], 0,0,0);
      }
    }
    __syncthreads();
  }
  int h = bh & 15;
  #pragma unroll
  for (int nd=0; nd<4; nd++){
    int d = nd*16 + l15;
    int c = h*64 + d;
    float4 v;
    v.x = acco[nd][0] / lrun[0];
    v.y = acco[nd][1] / lrun[1];
    v.z = acco[nd][2] / lrun[2];
    v.w = acco[nd][3] / lrun[3];
    size_t off = ((size_t)b*C_ + c)*T_ + (size_t)qblk*64 + wave*16 + lg*4;
    *(float4*)(out + off) = v;
  }
}

extern "C" void kernel_launch(void* const* d_in, const int* in_sizes, int n_in,
                              void* d_out, int out_size, void* d_ws, size_t ws_size,
                              hipStream_t stream) {
  const float* x    = (const float*)d_in[0];
  const int*   mask = (const int*)d_in[1];
  const float* Wmem = (const float*)d_in[2];
  const float* Wq   = (const float*)d_in[3];
  float* out = (float*)d_out;

  unsigned short* ws = (unsigned short*)d_ws;
  unsigned short* xT = ws;                                   // B*T*C
  unsigned short* Wc = xT + (size_t)B_*T_*C_;                // TC*C
  unsigned short* Qb = Wc + (size_t)TC*C_;                   // B*NH*T*DH
  unsigned short* Kb = Qb + (size_t)B_*NH*T_*DH;
  unsigned short* Vt = Kb + (size_t)B_*NH*T_*DH;

  cast_w_kernel<<<dim3(TC*C_/1024), dim3(256), 0, stream>>>(Wmem, Wq, Wc);
  transpose_x_kernel<<<dim3(T_/32, C_/32, B_), dim3(32,8), 0, stream>>>(x, xT);
  proj_gemm_kernel<<<dim3((TC/PBM)*(T_/PBN), B_), dim3(256), 0, stream>>>(Wc, xT, Kb, Vt, Qb);
  attn_kernel<<<dim3(T_/64, B_*NH), dim3(256), 0, stream>>>(Qb, Kb, Vt, mask, out);
}

// Round 2
// 253.345 us; speedup vs baseline: 1.2872x; 1.2872x over previous
//
#include <hip/hip_runtime.h>

#define B_ 4
#define C_ 1024
#define T_ 2048
#define NH 16
#define DH 64
#define TC 3072   // 3*C: rows [0,2048)=W_mem (K then V), [2048,3072)=W_q

typedef __attribute__((ext_vector_type(8))) short short8;
typedef __attribute__((ext_vector_type(4))) short short4v;
typedef __attribute__((ext_vector_type(4))) float f32x4;

static __device__ __forceinline__ unsigned short f2bf(float f){
  unsigned int u = __builtin_bit_cast(unsigned int, f);
  u += 0x7fffu + ((u >> 16) & 1u);
  return (unsigned short)(u >> 16);
}

// ---------------- cast W_mem||W_q -> bf16 Wc[3072][1024] ----------------
__global__ __launch_bounds__(256) void cast_w_kernel(const float* __restrict__ Wmem,
                                                     const float* __restrict__ Wq,
                                                     unsigned short* __restrict__ Wc){
  size_t base = ((size_t)blockIdx.x*256 + threadIdx.x)*4;
  float4 v;
  if (base < (size_t)2048*1024) v = *(const float4*)(Wmem + base);
  else                          v = *(const float4*)(Wq + (base - (size_t)2048*1024));
  short4v o;
  o.x = (short)f2bf(v.x); o.y = (short)f2bf(v.y);
  o.z = (short)f2bf(v.z); o.w = (short)f2bf(v.w);
  *(short4v*)(Wc + base) = o;
}

// ---------------- mask -> additive float bias (exact ref semantics) ----------------
__global__ __launch_bounds__(256) void mask_bias_kernel(const int* __restrict__ mask,
                                                        float* __restrict__ fbias){
  int i = blockIdx.x*256 + threadIdx.x;
  fbias[i] = mask[i] ? 0.f : -1e30f;
}

// ---------------- transpose-cast x[B][C][T] f32 -> xT[B][T][C] bf16 ----------------
__global__ __launch_bounds__(256) void transpose_x_kernel(const float* __restrict__ x,
                                                          unsigned short* __restrict__ xT){
  __shared__ float tile[32][33];
  int b = blockIdx.z;
  int c0 = blockIdx.y*32, t0 = blockIdx.x*32;
  int tx = threadIdx.x, ty = threadIdx.y;
  const float* xp = x + ((size_t)b*C_ + c0)*T_ + t0;
  #pragma unroll
  for (int i=0;i<4;i++) tile[ty+8*i][tx] = xp[(size_t)(ty+8*i)*T_ + tx];
  __syncthreads();
  unsigned short* op = xT + ((size_t)b*T_ + t0)*C_ + c0;
  #pragma unroll
  for (int i=0;i<4;i++) op[(size_t)(ty+8*i)*C_ + tx] = f2bf(tile[tx][ty+8*i]);
}

// ---------------- projection GEMM (m97 structure, unchanged) ----------------
#define PBM 128
#define PBN 128
#define PBK 64

__global__ __launch_bounds__(256) void proj_gemm_kernel(const unsigned short* __restrict__ Wc,
    const unsigned short* __restrict__ xT,
    unsigned short* __restrict__ Kb, unsigned short* __restrict__ Vt,
    unsigned short* __restrict__ Qb){
  __shared__ unsigned short sA[PBM*PBK];   // [128 o][64 c] linear
  __shared__ unsigned short sB[PBN*PBK];   // [128 t][64 c] linear
  int b = blockIdx.y;
  int nbn = T_/PBN;
  int o0 = (int)(blockIdx.x / nbn)*PBM;
  int t0 = (int)(blockIdx.x % nbn)*PBN;
  int tid = threadIdx.x;
  int lane = tid & 63, wave = tid >> 6;
  int wr = wave >> 1, wc = wave & 1;
  f32x4 acc[4][4] = {};
  const unsigned short* Abase = Wc + (size_t)o0*C_;
  const unsigned short* Bbase = xT + ((size_t)b*T_ + t0)*C_;
  auto ldsA = (__attribute__((address_space(3))) char*)sA;
  auto ldsB = (__attribute__((address_space(3))) char*)sB;
  for (int k0=0; k0<C_; k0+=PBK){
    #pragma unroll
    for (int i=0;i<4;i++){
      int L  = wave*4096 + i*1024;       // wave-uniform LDS base; HW adds lane*16
      int Ll = L + lane*16;
      int row = Ll >> 7;                 // /128 bytes per row
      int jb  = Ll & 127;
      const char* srcA = (const char*)(Abase + (size_t)row*C_ + k0) + jb;
      const char* srcB = (const char*)(Bbase + (size_t)row*C_ + k0) + jb;
      __builtin_amdgcn_global_load_lds((const __attribute__((address_space(1))) void*)srcA,
                                       (__attribute__((address_space(3))) void*)(ldsA + L), 16, 0, 0);
      __builtin_amdgcn_global_load_lds((const __attribute__((address_space(1))) void*)srcB,
                                       (__attribute__((address_space(3))) void*)(ldsB + L), 16, 0, 0);
    }
    __syncthreads();
    #pragma unroll
    for (int ks=0; ks<2; ks++){
      short8 af[4], bfr[4];
      #pragma unroll
      for (int m=0;m<4;m++){
        int row = wr*64 + m*16 + (lane & 15);
        af[m] = *(const short8*)((const char*)sA + row*128 + ks*64 + ((lane>>4)*16));
      }
      #pragma unroll
      for (int n=0;n<4;n++){
        int row = wc*64 + n*16 + (lane & 15);
        bfr[n] = *(const short8*)((const char*)sB + row*128 + ks*64 + ((lane>>4)*16));
      }
      #pragma unroll
      for (int m=0;m<4;m++){
        #pragma unroll
        for (int n=0;n<4;n++)
          acc[m][n] = __builtin_amdgcn_mfma_f32_16x16x32_bf16(af[m], bfr[n], acc[m][n], 0, 0, 0);
      }
    }
    __syncthreads();
  }
  int rowbase = o0 + wr*64;
  #pragma unroll
  for (int m=0;m<4;m++){
    int o = rowbase + m*16 + ((lane>>4)*4);
    #pragma unroll
    for (int n=0;n<4;n++){
      int t = t0 + wc*64 + n*16 + (lane & 15);
      f32x4 v = acc[m][n];
      if (o < C_){
        int h = o >> 6, d = o & 63;
        unsigned short* p = Kb + (((size_t)(b*NH + h)*T_ + t)*DH + d);
        short4v s; s.x=(short)f2bf(v.x); s.y=(short)f2bf(v.y);
        s.z=(short)f2bf(v.z); s.w=(short)f2bf(v.w);
        *(short4v*)p = s;
      } else if (o < 2*C_){
        int oo = o - C_;
        int h = oo >> 6, d = oo & 63;
        unsigned short* p = Vt + (((size_t)(b*NH + h)*DH + d)*T_ + t);
        p[0]    = f2bf(v.x);
        p[T_]   = f2bf(v.y);
        p[2*T_] = f2bf(v.z);
        p[3*T_] = f2bf(v.w);
      } else {
        int oo = o - 2*C_;
        int h = oo >> 6, d = oo & 63;
        unsigned short* p = Qb + (((size_t)(b*NH + h)*T_ + t)*DH + d);
        short4v s; s.x=(short)f2bf(v.x); s.y=(short)f2bf(v.y);
        s.z=(short)f2bf(v.z); s.w=(short)f2bf(v.w);
        *(short4v*)p = s;
      }
    }
  }
}

// ---------------- flash attention, swapped-QK^T lane-local softmax ----------------
// block = (b,h,qblk of 64 rows); 4 waves x 16 q-rows; KB=64 key tiles.
// QK^T computed as mfma(K,Q) -> lane holds S^T[key][q=l15]: softmax row is
// 16 in-register values + 2 cross-lg shuffles. P packed via cvt_pk -> b64 writes.
#define KB_ 64
#define PAD 88   // row stride in elems: 176 B -> 16B-aligned b128 reads, 2-way banks (free)

__global__ __launch_bounds__(256) void attn_kernel(const unsigned short* __restrict__ Qb,
    const unsigned short* __restrict__ Kb, const unsigned short* __restrict__ Vt,
    const float* __restrict__ fbias, float* __restrict__ out){
  __shared__ unsigned short sK[KB_][PAD];     // K tile [key][d]
  __shared__ unsigned short sV[DH][PAD];      // V tile transposed [d][key]
  __shared__ unsigned short sP[4][16][PAD];   // per-wave P [qrow(l15)][key]
  int qblk = blockIdx.x;
  int bh = blockIdx.y;
  int b = bh >> 4;
  int tid = threadIdx.x, lane = tid & 63, wave = tid >> 6;
  int l15 = lane & 15, lg = lane >> 4;
  const unsigned short* Kbase = Kb + (size_t)bh*T_*DH;
  const unsigned short* Vbase = Vt + (size_t)bh*DH*T_;
  const float* fbase = fbias + (size_t)b*T_;
  int qrow = qblk*64 + wave*16 + l15;
  const unsigned short* Qp = Qb + ((size_t)bh*T_ + qrow)*DH + lg*8;
  short8 qf0 = *(const short8*)(Qp);
  short8 qf1 = *(const short8*)(Qp + 32);
  f32x4 acco[4] = {};                 // out[q=lg*4+r][d=nd*16+l15]
  float mrun = -1e30f, lrun = 0.f;    // softmax state for q = l15 (dup across lg)
  const float s2 = 0.125f * 1.44269504088896340736f;  // scale * log2(e)
  for (int kt=0; kt<T_/KB_; kt++){
    #pragma unroll
    for (int i=0;i<2;i++){
      int chunk = tid + i*256;
      int row = chunk >> 3, c0 = (chunk & 7)*8;
      short8 kvv = *(const short8*)(Kbase + ((size_t)(kt*KB_ + row))*DH + c0);
      *(short8*)(&sK[row][c0]) = kvv;
      short8 vvv = *(const short8*)(Vbase + (size_t)row*T_ + kt*KB_ + c0);
      *(short8*)(&sV[row][c0]) = vvv;
    }
    // mask bias for this lane's 16 keys (issue before barrier to hide latency)
    float4 bias[4];
    #pragma unroll
    for (int n=0;n<4;n++) bias[n] = *(const float4*)(fbase + kt*KB_ + n*16 + lg*4);
    __syncthreads();
    // S^T = (Q K^T)^T : A=K rows=key, B=Q cols=q -> lane: q=l15, key=n*16+lg*4+r
    f32x4 sacc[4] = {};
    #pragma unroll
    for (int n=0;n<4;n++){
      short8 kf0 = *(const short8*)(&sK[n*16 + l15][lg*8]);
      short8 kf1 = *(const short8*)(&sK[n*16 + l15][32 + lg*8]);
      sacc[n] = __builtin_amdgcn_mfma_f32_16x16x32_bf16(kf0, qf0, sacc[n], 0,0,0);
      sacc[n] = __builtin_amdgcn_mfma_f32_16x16x32_bf16(kf1, qf1, sacc[n], 0,0,0);
    }
    float xv[16];
    #pragma unroll
    for (int n=0;n<4;n++){
      const float* bp = (const float*)&bias[n];
      #pragma unroll
      for (int r=0;r<4;r++) xv[n*4+r] = fmaf(sacc[n][r], s2, bp[r]);
    }
    float pmax = xv[0];
    #pragma unroll
    for (int j=1;j<16;j++) pmax = fmaxf(pmax, xv[j]);
    pmax = fmaxf(pmax, __shfl_xor(pmax, 16));
    pmax = fmaxf(pmax, __shfl_xor(pmax, 32));
    float mnew = fmaxf(mrun, pmax);
    float alpha = __builtin_amdgcn_exp2f(mrun - mnew);
    mrun = mnew;
    float pv[16];
    float psum = 0.f;
    #pragma unroll
    for (int j=0;j<16;j++){ pv[j] = __builtin_amdgcn_exp2f(xv[j] - mnew); psum += pv[j]; }
    psum += __shfl_xor(psum, 16);
    psum += __shfl_xor(psum, 32);
    lrun = lrun*alpha + psum;
    // broadcast alpha to the PV accumulator layout (q = lg*4 + r)
    #pragma unroll
    for (int r=0;r<4;r++){
      float ar = __shfl(alpha, lg*4 + r);
      #pragma unroll
      for (int nd=0; nd<4; nd++) acco[nd][r] *= ar;
    }
    // pack P (RNE via cvt_pk) and write 8B per n
    #pragma unroll
    for (int n=0;n<4;n++){
      unsigned int w0, w1;
      asm volatile("v_cvt_pk_bf16_f32 %0, %1, %2" : "=v"(w0) : "v"(pv[n*4+0]), "v"(pv[n*4+1]));
      asm volatile("v_cvt_pk_bf16_f32 %0, %1, %2" : "=v"(w1) : "v"(pv[n*4+2]), "v"(pv[n*4+3]));
      uint2 w; w.x = w0; w.y = w1;
      *(uint2*)(&sP[wave][l15][n*16 + lg*4]) = w;
    }
    // same-wave LDS write->read ordering
    asm volatile("s_waitcnt lgkmcnt(0)" ::: "memory");
    #pragma unroll
    for (int ks=0; ks<2; ks++){
      short8 pf = *(const short8*)(&sP[wave][l15][ks*32 + lg*8]);
      #pragma unroll
      for (int nd=0; nd<4; nd++){
        short8 vf = *(const short8*)(&sV[nd*16 + l15][ks*32 + lg*8]);
        acco[nd] = __builtin_amdgcn_mfma_f32_16x16x32_bf16(pf, vf, acco[nd], 0,0,0);
      }
    }
    __syncthreads();
  }
  float rl[4];
  #pragma unroll
  for (int r=0;r<4;r++) rl[r] = 1.0f / __shfl(lrun, lg*4 + r);
  int h = bh & 15;
  #pragma unroll
  for (int nd=0; nd<4; nd++){
    int d = nd*16 + l15;
    int c = h*64 + d;
    float4 v;
    v.x = acco[nd][0] * rl[0];
    v.y = acco[nd][1] * rl[1];
    v.z = acco[nd][2] * rl[2];
    v.w = acco[nd][3] * rl[3];
    size_t off = ((size_t)b*C_ + c)*T_ + (size_t)qblk*64 + wave*16 + lg*4;
    *(float4*)(out + off) = v;
  }
}

extern "C" void kernel_launch(void* const* d_in, const int* in_sizes, int n_in,
                              void* d_out, int out_size, void* d_ws, size_t ws_size,
                              hipStream_t stream) {
  const float* x    = (const float*)d_in[0];
  const int*   mask = (const int*)d_in[1];
  const float* Wmem = (const float*)d_in[2];
  const float* Wq   = (const float*)d_in[3];
  float* out = (float*)d_out;

  unsigned short* ws = (unsigned short*)d_ws;
  unsigned short* xT = ws;                                   // B*T*C
  unsigned short* Wc = xT + (size_t)B_*T_*C_;                // TC*C
  unsigned short* Qb = Wc + (size_t)TC*C_;                   // B*NH*T*DH
  unsigned short* Kb = Qb + (size_t)B_*NH*T_*DH;
  unsigned short* Vt = Kb + (size_t)B_*NH*T_*DH;
  float* fbias = (float*)(Vt + (size_t)B_*NH*T_*DH);         // B*T floats

  cast_w_kernel<<<dim3(TC*C_/1024), dim3(256), 0, stream>>>(Wmem, Wq, Wc);
  mask_bias_kernel<<<dim3(B_*T_/256), dim3(256), 0, stream>>>(mask, fbias);
  transpose_x_kernel<<<dim3(T_/32, C_/32, B_), dim3(32,8), 0, stream>>>(x, xT);
  proj_gemm_kernel<<<dim3((TC/PBM)*(T_/PBN), B_), dim3(256), 0, stream>>>(Wc, xT, Kb, Vt, Qb);
  attn_kernel<<<dim3(T_/64, B_*NH), dim3(256), 0, stream>>>(Qb, Kb, Vt, fbias, out);
}

// Round 3
// 223.179 us; speedup vs baseline: 1.4612x; 1.1352x over previous
//
#include <hip/hip_runtime.h>

#define B_ 4
#define C_ 1024
#define T_ 2048
#define NH 16
#define DH 64
#define TC 3072   // 3*C: rows [0,2048)=W_mem (K then V), [2048,3072)=W_q

typedef __attribute__((ext_vector_type(8))) short short8;
typedef __attribute__((ext_vector_type(4))) short short4v;
typedef __attribute__((ext_vector_type(4))) float f32x4;

static __device__ __forceinline__ unsigned short f2bf(float f){
  unsigned int u = __builtin_bit_cast(unsigned int, f);
  u += 0x7fffu + ((u >> 16) & 1u);
  return (unsigned short)(u >> 16);
}

// ---------------- cast W_mem||W_q -> bf16 Wc[3072][1024] ----------------
__global__ __launch_bounds__(256) void cast_w_kernel(const float* __restrict__ Wmem,
                                                     const float* __restrict__ Wq,
                                                     unsigned short* __restrict__ Wc){
  size_t base = ((size_t)blockIdx.x*256 + threadIdx.x)*4;
  float4 v;
  if (base < (size_t)2048*1024) v = *(const float4*)(Wmem + base);
  else                          v = *(const float4*)(Wq + (base - (size_t)2048*1024));
  short4v o;
  o.x = (short)f2bf(v.x); o.y = (short)f2bf(v.y);
  o.z = (short)f2bf(v.z); o.w = (short)f2bf(v.w);
  *(short4v*)(Wc + base) = o;
}

// ---------------- mask -> additive float bias (exact ref semantics) ----------------
__global__ __launch_bounds__(256) void mask_bias_kernel(const int* __restrict__ mask,
                                                        float* __restrict__ fbias){
  int i = blockIdx.x*256 + threadIdx.x;
  fbias[i] = mask[i] ? 0.f : -1e30f;
}

// ---------------- transpose-cast x[B][C][T] f32 -> xT[B][T][C] bf16 ----------------
__global__ __launch_bounds__(256) void transpose_x_kernel(const float* __restrict__ x,
                                                          unsigned short* __restrict__ xT){
  __shared__ float tile[32][33];
  int b = blockIdx.z;
  int c0 = blockIdx.y*32, t0 = blockIdx.x*32;
  int tx = threadIdx.x, ty = threadIdx.y;
  const float* xp = x + ((size_t)b*C_ + c0)*T_ + t0;
  #pragma unroll
  for (int i=0;i<4;i++) tile[ty+8*i][tx] = xp[(size_t)(ty+8*i)*T_ + tx];
  __syncthreads();
  unsigned short* op = xT + ((size_t)b*T_ + t0)*C_ + c0;
  #pragma unroll
  for (int i=0;i<4;i++) op[(size_t)(ty+8*i)*C_ + tx] = f2bf(tile[tx][ty+8*i]);
}

// ---------------- projection GEMM (m97 structure, unchanged) ----------------
#define PBM 128
#define PBN 128
#define PBK 64

__global__ __launch_bounds__(256) void proj_gemm_kernel(const unsigned short* __restrict__ Wc,
    const unsigned short* __restrict__ xT,
    unsigned short* __restrict__ Kb, unsigned short* __restrict__ Vt,
    unsigned short* __restrict__ Qb){
  __shared__ unsigned short sA[PBM*PBK];
  __shared__ unsigned short sB[PBN*PBK];
  int b = blockIdx.y;
  int nbn = T_/PBN;
  int o0 = (int)(blockIdx.x / nbn)*PBM;
  int t0 = (int)(blockIdx.x % nbn)*PBN;
  int tid = threadIdx.x;
  int lane = tid & 63, wave = tid >> 6;
  int wr = wave >> 1, wc = wave & 1;
  f32x4 acc[4][4] = {};
  const unsigned short* Abase = Wc + (size_t)o0*C_;
  const unsigned short* Bbase = xT + ((size_t)b*T_ + t0)*C_;
  auto ldsA = (__attribute__((address_space(3))) char*)sA;
  auto ldsB = (__attribute__((address_space(3))) char*)sB;
  for (int k0=0; k0<C_; k0+=PBK){
    #pragma unroll
    for (int i=0;i<4;i++){
      int L  = wave*4096 + i*1024;
      int Ll = L + lane*16;
      int row = Ll >> 7;
      int jb  = Ll & 127;
      const char* srcA = (const char*)(Abase + (size_t)row*C_ + k0) + jb;
      const char* srcB = (const char*)(Bbase + (size_t)row*C_ + k0) + jb;
      __builtin_amdgcn_global_load_lds((const __attribute__((address_space(1))) void*)srcA,
                                       (__attribute__((address_space(3))) void*)(ldsA + L), 16, 0, 0);
      __builtin_amdgcn_global_load_lds((const __attribute__((address_space(1))) void*)srcB,
                                       (__attribute__((address_space(3))) void*)(ldsB + L), 16, 0, 0);
    }
    __syncthreads();
    #pragma unroll
    for (int ks=0; ks<2; ks++){
      short8 af[4], bfr[4];
      #pragma unroll
      for (int m=0;m<4;m++){
        int row = wr*64 + m*16 + (lane & 15);
        af[m] = *(const short8*)((const char*)sA + row*128 + ks*64 + ((lane>>4)*16));
      }
      #pragma unroll
      for (int n=0;n<4;n++){
        int row = wc*64 + n*16 + (lane & 15);
        bfr[n] = *(const short8*)((const char*)sB + row*128 + ks*64 + ((lane>>4)*16));
      }
      #pragma unroll
      for (int m=0;m<4;m++){
        #pragma unroll
        for (int n=0;n<4;n++)
          acc[m][n] = __builtin_amdgcn_mfma_f32_16x16x32_bf16(af[m], bfr[n], acc[m][n], 0, 0, 0);
      }
    }
    __syncthreads();
  }
  int rowbase = o0 + wr*64;
  #pragma unroll
  for (int m=0;m<4;m++){
    int o = rowbase + m*16 + ((lane>>4)*4);
    #pragma unroll
    for (int n=0;n<4;n++){
      int t = t0 + wc*64 + n*16 + (lane & 15);
      f32x4 v = acc[m][n];
      if (o < C_){
        int h = o >> 6, d = o & 63;
        unsigned short* p = Kb + (((size_t)(b*NH + h)*T_ + t)*DH + d);
        short4v s; s.x=(short)f2bf(v.x); s.y=(short)f2bf(v.y);
        s.z=(short)f2bf(v.z); s.w=(short)f2bf(v.w);
        *(short4v*)p = s;
      } else if (o < 2*C_){
        int oo = o - C_;
        int h = oo >> 6, d = oo & 63;
        unsigned short* p = Vt + (((size_t)(b*NH + h)*DH + d)*T_ + t);
        p[0]    = f2bf(v.x);
        p[T_]   = f2bf(v.y);
        p[2*T_] = f2bf(v.z);
        p[3*T_] = f2bf(v.w);
      } else {
        int oo = o - 2*C_;
        int h = oo >> 6, d = oo & 63;
        unsigned short* p = Qb + (((size_t)(b*NH + h)*T_ + t)*DH + d);
        short4v s; s.x=(short)f2bf(v.x); s.y=(short)f2bf(v.y);
        s.z=(short)f2bf(v.z); s.w=(short)f2bf(v.w);
        *(short4v*)p = s;
      }
    }
  }
}

// ---------------- flash attention: swizzled LDS + dbuf global_load_lds + defer-max ----------------
// [64][64] tiles, 128B rows. 16B-chunk XOR swizzle: lds_chunk = src_chunk ^ (row&7).
// Staging: linear LDS dest (wave-uniform + lane*16), inverse-swizzled per-lane global src.
#define KB_ 64

__global__ __launch_bounds__(256) void attn_kernel(const unsigned short* __restrict__ Qb,
    const unsigned short* __restrict__ Kb, const unsigned short* __restrict__ Vt,
    const float* __restrict__ fbias, float* __restrict__ out){
  __shared__ unsigned short sK[2][KB_*DH];   // [key][d] swizzled, double-buffered
  __shared__ unsigned short sV[2][KB_*DH];   // [d][key] swizzled, double-buffered
  __shared__ unsigned short sP[4][16*KB_];   // per-wave [q(l15)][key] swizzled
  const int qblk = blockIdx.x, bh = blockIdx.y, b = bh >> 4;
  const int tid = threadIdx.x, lane = tid & 63, wave = tid >> 6;
  const int l15 = lane & 15, lg = lane >> 4;
  const int rsw = l15 & 7;
  const int cA = (lg ^ rsw) << 4;            // swizzled base chunk-byte for reads
  const unsigned short* Kbase = Kb + (size_t)bh*T_*DH;
  const unsigned short* Vbase = Vt + (size_t)bh*DH*T_;
  const float* fbase = fbias + (size_t)b*T_;
  const int qrow = qblk*64 + wave*16 + l15;
  const unsigned short* Qp = Qb + ((size_t)bh*T_ + qrow)*DH + lg*8;
  short8 qf0 = *(const short8*)(Qp);
  short8 qf1 = *(const short8*)(Qp + 32);
  f32x4 acco[4] = {};                 // out[q=lg*4+r][d=nd*16+l15]
  float mrun = -1e30f, lpart = 0.f;   // per-lane state: q=l15, partial sum over own keys
  const float s2 = 0.125f * 1.44269504088896340736f;  // scale * log2(e)

  // per-lane staging source addresses (inverse swizzle: LDS chunk cs holds src chunk cs^(row&7))
  const int L0  = wave*2048;
  const int Ll0 = L0 + lane*16, Ll1 = Ll0 + 1024;
  const int row0 = Ll0 >> 7, row1 = Ll1 >> 7;
  const int cg0 = ((Ll0 >> 4) & 7) ^ (row0 & 7);
  const int cg1 = ((Ll1 >> 4) & 7) ^ (row1 & 7);
  const char* srcK0 = (const char*)Kbase + row0*128 + cg0*16;
  const char* srcK1 = (const char*)Kbase + row1*128 + cg1*16;
  const char* srcV0 = (const char*)Vbase + (size_t)row0*(T_*2) + cg0*16;
  const char* srcV1 = (const char*)Vbase + (size_t)row1*(T_*2) + cg1*16;

  auto STAGE = [&](int buf) {
    auto ldsK = (__attribute__((address_space(3))) char*)&sK[buf][0];
    auto ldsV = (__attribute__((address_space(3))) char*)&sV[buf][0];
    __builtin_amdgcn_global_load_lds((const __attribute__((address_space(1))) void*)srcK0,
        (__attribute__((address_space(3))) void*)(ldsK + L0), 16, 0, 0);
    __builtin_amdgcn_global_load_lds((const __attribute__((address_space(1))) void*)srcK1,
        (__attribute__((address_space(3))) void*)(ldsK + L0 + 1024), 16, 0, 0);
    __builtin_amdgcn_global_load_lds((const __attribute__((address_space(1))) void*)srcV0,
        (__attribute__((address_space(3))) void*)(ldsV + L0), 16, 0, 0);
    __builtin_amdgcn_global_load_lds((const __attribute__((address_space(1))) void*)srcV1,
        (__attribute__((address_space(3))) void*)(ldsV + L0 + 1024), 16, 0, 0);
    srcK0 += KB_*DH*2; srcK1 += KB_*DH*2;   // next K tile: +8192 B
    srcV0 += KB_*2;    srcV1 += KB_*2;      // next V tile: +128 B per row
  };

  STAGE(0);
  __syncthreads();   // drain prologue staging

  char* sPw = (char*)&sP[wave][0];

  for (int kt2 = 0; kt2 < T_/KB_/2; kt2++){
    #pragma unroll
    for (int half = 0; half < 2; half++){
      const int kt = kt2*2 + half;
      // bias loads first (their waitcnt then tolerates outstanding stage loads)
      float4 bias[4];
      #pragma unroll
      for (int n=0;n<4;n++) bias[n] = *(const float4*)(fbase + kt*KB_ + n*16 + lg*4);
      // prefetch next tile into the other buffer (overlaps with compute below)
      if (kt < T_/KB_ - 1) STAGE(half ^ 1);
      // ---- QK^T (swapped): lane holds S^T[key=n*16+lg*4+r][q=l15] ----
      const char* sKb = (const char*)&sK[half][0] + l15*128;
      const char* sVb = (const char*)&sV[half][0] + l15*128;
      f32x4 sacc[4] = {};
      __builtin_amdgcn_s_setprio(1);
      #pragma unroll
      for (int n=0;n<4;n++){
        short8 kf0 = *(const short8*)(sKb + n*2048 + cA);
        short8 kf1 = *(const short8*)(sKb + n*2048 + (cA ^ 64));
        sacc[n] = __builtin_amdgcn_mfma_f32_16x16x32_bf16(kf0, qf0, sacc[n], 0,0,0);
        sacc[n] = __builtin_amdgcn_mfma_f32_16x16x32_bf16(kf1, qf1, sacc[n], 0,0,0);
      }
      __builtin_amdgcn_s_setprio(0);
      // ---- softmax (lane-local, defer-max) ----
      float xv[16];
      #pragma unroll
      for (int n=0;n<4;n++){
        const float* bp = (const float*)&bias[n];
        #pragma unroll
        for (int r=0;r<4;r++) xv[n*4+r] = fmaf(sacc[n][r], s2, bp[r]);
      }
      float pmax = fmaxf(fmaxf(xv[0],xv[1]), fmaxf(xv[2],xv[3]));
      float pm1  = fmaxf(fmaxf(xv[4],xv[5]), fmaxf(xv[6],xv[7]));
      float pm2  = fmaxf(fmaxf(xv[8],xv[9]), fmaxf(xv[10],xv[11]));
      float pm3  = fmaxf(fmaxf(xv[12],xv[13]), fmaxf(xv[14],xv[15]));
      pmax = fmaxf(fmaxf(pmax,pm1), fmaxf(pm2,pm3));
      if (!__all(pmax - mrun <= 8.0f)){
        float pm = fmaxf(pmax, __shfl_xor(pmax, 16));
        pm = fmaxf(pm, __shfl_xor(pm, 32));
        float mnew = fmaxf(mrun, pm);
        float alpha = __builtin_amdgcn_exp2f(mrun - mnew);
        mrun = mnew;
        lpart *= alpha;
        #pragma unroll
        for (int r=0;r<4;r++){
          float ar = __shfl(alpha, lg*4 + r);
          #pragma unroll
          for (int nd=0; nd<4; nd++) acco[nd][r] *= ar;
        }
      }
      float pv[16];
      float ps = 0.f;
      #pragma unroll
      for (int j=0;j<16;j++){ pv[j] = __builtin_amdgcn_exp2f(xv[j] - mrun); ps += pv[j]; }
      lpart += ps;
      // ---- pack P -> LDS (swizzled 8B writes) ----
      #pragma unroll
      for (int n=0;n<4;n++){
        unsigned int w0, w1;
        asm volatile("v_cvt_pk_bf16_f32 %0, %1, %2" : "=v"(w0) : "v"(pv[n*4+0]), "v"(pv[n*4+1]));
        asm volatile("v_cvt_pk_bf16_f32 %0, %1, %2" : "=v"(w1) : "v"(pv[n*4+2]), "v"(pv[n*4+3]));
        uint2 w; w.x = w0; w.y = w1;
        int off = (((n*2 + (lg>>1)) ^ rsw) << 4) | ((lg & 1) << 3);
        *(uint2*)(sPw + l15*128 + off) = w;
      }
      asm volatile("s_waitcnt lgkmcnt(0)" ::: "memory");
      __builtin_amdgcn_sched_barrier(0);
      // ---- PV ----
      __builtin_amdgcn_s_setprio(1);
      #pragma unroll
      for (int ks=0; ks<2; ks++){
        short8 pf = *(const short8*)(sPw + l15*128 + (cA ^ (ks<<6)));
        #pragma unroll
        for (int nd=0; nd<4; nd++){
          short8 vf = *(const short8*)(sVb + nd*2048 + (cA ^ (ks<<6)));
          acco[nd] = __builtin_amdgcn_mfma_f32_16x16x32_bf16(pf, vf, acco[nd], 0,0,0);
        }
      }
      __builtin_amdgcn_s_setprio(0);
      __syncthreads();   // next buffer staged (vmcnt drain) + this buffer free
    }
  }
  // epilogue: reduce l across lg groups, normalize, write out[b][c][t] f32
  float lt = lpart + __shfl_xor(lpart, 16);
  lt += __shfl_xor(lt, 32);
  float rl[4];
  #pragma unroll
  for (int r=0;r<4;r++) rl[r] = 1.0f / __shfl(lt, lg*4 + r);
  int h = bh & 15;
  #pragma unroll
  for (int nd=0; nd<4; nd++){
    int d = nd*16 + l15;
    int c = h*64 + d;
    float4 v;
    v.x = acco[nd][0] * rl[0];
    v.y = acco[nd][1] * rl[1];
    v.z = acco[nd][2] * rl[2];
    v.w = acco[nd][3] * rl[3];
    size_t off = ((size_t)b*C_ + c)*T_ + (size_t)qblk*64 + wave*16 + lg*4;
    *(float4*)(out + off) = v;
  }
}

extern "C" void kernel_launch(void* const* d_in, const int* in_sizes, int n_in,
                              void* d_out, int out_size, void* d_ws, size_t ws_size,
                              hipStream_t stream) {
  const float* x    = (const float*)d_in[0];
  const int*   mask = (const int*)d_in[1];
  const float* Wmem = (const float*)d_in[2];
  const float* Wq   = (const float*)d_in[3];
  float* out = (float*)d_out;

  unsigned short* ws = (unsigned short*)d_ws;
  unsigned short* xT = ws;                                   // B*T*C
  unsigned short* Wc = xT + (size_t)B_*T_*C_;                // TC*C
  unsigned short* Qb = Wc + (size_t)TC*C_;                   // B*NH*T*DH
  unsigned short* Kb = Qb + (size_t)B_*NH*T_*DH;
  unsigned short* Vt = Kb + (size_t)B_*NH*T_*DH;
  float* fbias = (float*)(Vt + (size_t)B_*NH*T_*DH);         // B*T floats

  cast_w_kernel<<<dim3(TC*C_/1024), dim3(256), 0, stream>>>(Wmem, Wq, Wc);
  mask_bias_kernel<<<dim3(B_*T_/256), dim3(256), 0, stream>>>(mask, fbias);
  transpose_x_kernel<<<dim3(T_/32, C_/32, B_), dim3(32,8), 0, stream>>>(x, xT);
  proj_gemm_kernel<<<dim3((TC/PBM)*(T_/PBN), B_), dim3(256), 0, stream>>>(Wc, xT, Kb, Vt, Qb);
  attn_kernel<<<dim3(T_/64, B_*NH), dim3(256), 0, stream>>>(Qb, Kb, Vt, fbias, out);
}